// Round 1
// baseline (643.185 us; speedup 1.0000x reference)
//
#include <hip/hip_runtime.h>

constexpr int NB = 8, NA = 64, NT = 12, NH = 128, NE = 128, NTY = 8, NSC = 32, NAG = 16;
constexpr int ROWS = 4;   // agent-rows per k_step block

struct Params {
    const float *traj, *ntraj, *ty, *sd, *adata, *rel;
    const float *W_in, *b_in, *W_nt, *b_nt, *W_ag, *b_ag, *W_sc, *b_sc;
    const float *W_ein, *b_ein, *W_ety, *b_ety;
    const float *W_edge, *b_edge, *W_self, *b_self, *W_e2n, *b_e2n;
    const float *W_ih, *W_hh, *b_ih, *b_hh, *W_pred, *b_pred;
    float *h, *c, *se, *R, *sumhW2, *out;
};

// R0[b,i,:] = sum_j edge0[b,i,j,:] computed in closed form.
// edge0 = [f_i|f_j|ty_i|ty_j] @ W_ein + b_ein + [ty_i|ty_j] @ W_ety + b_ety
__global__ void k_r0(Params p) {
    const int row = blockIdx.x;        // b*NA + i
    const int n = threadIdx.x;         // 128 threads
    const int b = row / NA;
    const int i = row % NA;
    __shared__ float lf[NA][6];
    __shared__ float lt[NA][NTY];
    __shared__ float sumf[6];
    __shared__ float sumt[NTY];
    if (threadIdx.x < NA) {
        int j = threadIdx.x, rj = b * NA + j;
        for (int k = 0; k < 3; ++k) {
            lf[j][k]     = p.ntraj[(rj * NT + 0) * 3 + k];
            lf[j][3 + k] = p.traj [(rj * NT + 0) * 3 + k];
        }
        for (int k = 0; k < NTY; ++k) lt[j][k] = p.ty[rj * NTY + k];
    }
    __syncthreads();
    if (threadIdx.x < 6) {
        float s = 0.f;
        for (int j = 0; j < NA; ++j) s += lf[j][threadIdx.x];
        sumf[threadIdx.x] = s;
    } else if (threadIdx.x < 6 + NTY) {
        int k = threadIdx.x - 6;
        float s = 0.f;
        for (int j = 0; j < NA; ++j) s += lt[j][k];
        sumt[k] = s;
    }
    __syncthreads();
    float acc_i = p.b_ein[n] + p.b_ety[n];
    for (int k = 0; k < 6; ++k)   acc_i += lf[i][k] * p.W_ein[k * NE + n];
    for (int k = 0; k < NTY; ++k) acc_i += lt[i][k] * (p.W_ein[(12 + k) * NE + n] + p.W_ety[k * NE + n]);
    float acc_j = 0.f;
    for (int k = 0; k < 6; ++k)   acc_j += sumf[k] * p.W_ein[(6 + k) * NE + n];
    for (int k = 0; k < NTY; ++k) acc_j += sumt[k] * (p.W_ein[(20 + k) * NE + n] + p.W_ety[(NTY + k) * NE + n]);
    p.R[row * NE + n] = 64.f * acc_i + acc_j;
}

// sumhW2[b,:] = (sum_i h[b,i,:]) @ W_edge[128:256,:]
__global__ void k_sumhw2(Params p) {
    const int b = blockIdx.x, n = threadIdx.x;   // 8 blocks x 128 threads
    __shared__ float lds[NH];
    float s = 0.f;
    for (int i = 0; i < NA; ++i) s += p.h[(b * NA + i) * NH + n];
    lds[n] = s;
    __syncthreads();
    float acc = 0.f;
    for (int k = 0; k < NH; ++k) acc += lds[k] * p.W_edge[(NH + k) * NE + n];
    p.sumhW2[b * NH + n] = acc;
}

// One full recurrence step for ROWS agent-rows (all row-local given sumhW2).
__global__ __launch_bounds__(256) void k_step(Params p, int t) {
    const int r0 = blockIdx.x * ROWS;     // global row = b*NA + a
    const int b = r0 / NA;
    const int tid = threadIdx.x;

    __shared__ float lh[ROWS][NH];
    __shared__ float lR[ROWS][NH];
    __shared__ float lse[ROWS][NH];
    __shared__ float lagg[ROWS][NE];
    __shared__ float lx[ROWS][5 * NH];
    __shared__ float lg[ROWS][4 * NH];

    // Load carried state rows.
    for (int idx = tid; idx < ROWS * NH; idx += 256) {
        int r = idx >> 7, k = idx & (NH - 1);
        lh[r][k]  = p.h [(r0 + r) * NH + k];
        lR[r][k]  = p.R [(r0 + r) * NH + k];
        lse[r][k] = p.se[(r0 + r) * NH + k];
    }
    // Prefill x = [coord | type_enc | node_edges(later) | scene | agent] on the fly.
    {
        const int n = tid & (NH - 1);
        const int rh = tid >> 7;
        for (int rr = 0; rr < ROWS / 2; ++rr) {
            const int r = rh * (ROWS / 2) + rr;
            const int g = r0 + r;
            float acc = p.b_in[n];
            for (int k = 0; k < 3; ++k) acc += p.ntraj[(g * NT + t) * 3 + k] * p.W_in[k * NH + n];
            for (int k = 0; k < 3; ++k) acc += p.traj [(g * NT + t) * 3 + k] * p.W_in[(3 + k) * NH + n];
            lx[r][n] = fmaxf(acc, 0.f);                       // coord (relu)
            acc = p.b_nt[n];
            for (int k = 0; k < NTY; ++k) acc += p.ty[g * NTY + k] * p.W_nt[k * NH + n];
            lx[r][NH + n] = acc;                              // type_enc
            acc = p.b_sc[n];
            for (int k = 0; k < NSC; ++k) acc += p.sd[(b * NT + t) * NSC + k] * p.W_sc[k * NH + n];
            lx[r][3 * NH + n] = acc;                          // scene_enc (broadcast over agents)
            acc = p.b_ag[n];
            for (int k = 0; k < NAG; ++k) acc += p.adata[(g * NT + t) * NAG + k] * p.W_ag[k * NH + n];
            lx[r][4 * NH + n] = acc * p.rel[g];               // agent_enc
        }
    }
    __syncthreads();

    // Phase A: hW1, R@W3, se_new; produce R_new, se_new, agg.
    {
        const int n = tid & (NH - 1);
        const int rh = tid >> 7;
        float a1[ROWS / 2] = {}, a3[ROWS / 2] = {}, aS[ROWS / 2] = {};
        for (int k = 0; k < NH; ++k) {
            float w1 = p.W_edge[k * NE + n];
            float w3 = p.W_edge[(2 * NH + k) * NE + n];
            float wsA = p.W_self[k * NE + n];
            float wsB = p.W_self[(NH + k) * NE + n];
#pragma unroll
            for (int rr = 0; rr < ROWS / 2; ++rr) {
                const int r = rh * (ROWS / 2) + rr;
                a1[rr] += lh[r][k] * w1;
                a3[rr] += lR[r][k] * w3;
                aS[rr] += lh[r][k] * wsA + lse[r][k] * wsB;
            }
        }
#pragma unroll
        for (int kk = 0; kk < NTY; ++kk) {
            float wsT = p.W_self[(2 * NH + kk) * NE + n];
            for (int rr = 0; rr < ROWS / 2; ++rr) {
                const int r = rh * (ROWS / 2) + rr;
                aS[rr] += p.ty[(r0 + r) * NTY + kk] * wsT;
            }
        }
        const float shw2 = p.sumhW2[b * NH + n];
        const float be = p.b_edge[n], bs = p.b_self[n];
        for (int rr = 0; rr < ROWS / 2; ++rr) {
            const int r = rh * (ROWS / 2) + rr;
            float Rn = 64.f * a1[rr] + shw2 + a3[rr] + 64.f * be;   // = es_new.sum(axis=2)
            float sn = aS[rr] + bs;                                  // se_new
            p.R [(r0 + r) * NH + n] = Rn;
            p.se[(r0 + r) * NH + n] = sn;
            lagg[r][n] = Rn + sn;                                    // agg
        }
    }
    __syncthreads();

    // Phase B: node_edges = (t>0) * (agg @ W_e2n + b_e2n)  ->  lx[:, 2H:3H]
    {
        const int n = tid & (NH - 1);
        const int rh = tid >> 7;
        for (int rr = 0; rr < ROWS / 2; ++rr) {
            const int r = rh * (ROWS / 2) + rr;
            float acc = p.b_e2n[n];
            for (int k = 0; k < NE; ++k) acc += lagg[r][k] * p.W_e2n[k * NH + n];
            lx[r][2 * NH + n] = (t > 0) ? acc : 0.f;
        }
    }
    __syncthreads();

    // Phase C: gates = x @ W_ih + h @ W_hh + b_ih + b_hh   (512 cols; thread owns {tid, tid+256})
    {
        float acc[ROWS][2];
#pragma unroll
        for (int r = 0; r < ROWS; ++r) { acc[r][0] = 0.f; acc[r][1] = 0.f; }
        const int n0 = tid, n1 = tid + 256;
#pragma unroll 4
        for (int k = 0; k < 5 * NH; ++k) {
            float w0 = p.W_ih[k * (4 * NH) + n0];
            float w1 = p.W_ih[k * (4 * NH) + n1];
#pragma unroll
            for (int r = 0; r < ROWS; ++r) {
                float xv = lx[r][k];
                acc[r][0] += xv * w0;
                acc[r][1] += xv * w1;
            }
        }
#pragma unroll 4
        for (int k = 0; k < NH; ++k) {
            float w0 = p.W_hh[k * (4 * NH) + n0];
            float w1 = p.W_hh[k * (4 * NH) + n1];
#pragma unroll
            for (int r = 0; r < ROWS; ++r) {
                float hv = lh[r][k];
                acc[r][0] += hv * w0;
                acc[r][1] += hv * w1;
            }
        }
        const float bb0 = p.b_ih[n0] + p.b_hh[n0];
        const float bb1 = p.b_ih[n1] + p.b_hh[n1];
#pragma unroll
        for (int r = 0; r < ROWS; ++r) {
            lg[r][n0] = acc[r][0] + bb0;
            lg[r][n1] = acc[r][1] + bb1;
        }
    }
    __syncthreads();

    // Phase D: LSTM elementwise; write h,c; refresh lh with h_new.
    for (int idx = tid; idx < ROWS * NH; idx += 256) {
        const int r = idx >> 7, n = idx & (NH - 1);
        float gi = lg[r][n];
        float gf = lg[r][NH + n];
        float gg = lg[r][2 * NH + n];
        float go = lg[r][3 * NH + n];
        float si = 1.f / (1.f + expf(-gi));
        float sf = 1.f / (1.f + expf(-gf));
        float so = 1.f / (1.f + expf(-go));
        float cn = sf * p.c[(r0 + r) * NH + n] + si * tanhf(gg);
        float hn = so * tanhf(cn);
        p.c[(r0 + r) * NH + n] = cn;
        p.h[(r0 + r) * NH + n] = hn;
        lh[r][n] = hn;
    }
    __syncthreads();

    // Phase E: out[b,a,t,:] = relu(h_new @ W_pred + b_pred)
    {
        const int n = tid & (NH - 1);
        const int rh = tid >> 7;
        for (int rr = 0; rr < ROWS / 2; ++rr) {
            const int r = rh * (ROWS / 2) + rr;
            float acc = p.b_pred[n];
            for (int k = 0; k < NH; ++k) acc += lh[r][k] * p.W_pred[k * NH + n];
            p.out[((r0 + r) * NT + t) * NH + n] = fmaxf(acc, 0.f);
        }
    }
}

extern "C" void kernel_launch(void* const* d_in, const int* in_sizes, int n_in,
                              void* d_out, int out_size, void* d_ws, size_t ws_size,
                              hipStream_t stream) {
    const float* const* in = (const float* const*)d_in;
    Params p;
    p.traj = in[0]; p.ntraj = in[1]; p.ty = in[2]; p.sd = in[3]; p.adata = in[4]; p.rel = in[5];
    p.W_in = in[6]; p.b_in = in[7]; p.W_nt = in[8]; p.b_nt = in[9];
    p.W_ag = in[10]; p.b_ag = in[11]; p.W_sc = in[12]; p.b_sc = in[13];
    p.W_ein = in[14]; p.b_ein = in[15]; p.W_ety = in[16]; p.b_ety = in[17];
    p.W_edge = in[18]; p.b_edge = in[19]; p.W_self = in[20]; p.b_self = in[21];
    p.W_e2n = in[22]; p.b_e2n = in[23];
    p.W_ih = in[24]; p.W_hh = in[25]; p.b_ih = in[26]; p.b_hh = in[27];
    p.W_pred = in[28]; p.b_pred = in[29];

    float* ws = (float*)d_ws;
    const int S = NB * NA * NH;       // 65536 floats per state tensor
    p.h = ws;                          // zero-init each call
    p.c = ws + S;                      // zero-init each call
    p.se = ws + 2 * S;                 // zero-init each call
    p.R = ws + 3 * S;                  // fully written by k_r0
    p.sumhW2 = ws + 4 * S;             // fully written by k_sumhw2 before use
    p.out = (float*)d_out;

    hipMemsetAsync(p.h, 0, 3 * S * sizeof(float), stream);   // h, c, se contiguous
    k_r0<<<NB * NA, 128, 0, stream>>>(p);
    for (int t = 0; t < NT; ++t) {
        k_sumhw2<<<NB, NH, 0, stream>>>(p);
        k_step<<<NB * NA / ROWS, 256, 0, stream>>>(p, t);
    }
}

// Round 3
// 241.342 us; speedup vs baseline: 2.6650x; 2.6650x over previous
//
#include <hip/hip_runtime.h>

constexpr int NB = 8, NA = 64, NT = 12, NH = 128, NTY = 8, NSC = 32, NAG = 16;

struct Params {
    const float *traj, *ntraj, *ty, *sd, *adata, *rel;
    const float *W_in, *b_in, *W_nt, *b_nt, *W_ag, *b_ag, *W_sc, *b_sc;
    const float *W_ein, *b_ein, *W_ety, *b_ety;
    const float *W_edge, *b_edge, *W_self, *b_self, *W_e2n, *b_e2n;
    const float *W_ih, *W_hh, *b_ih, *b_hh, *W_pred, *b_pred;
    float *h0, *h1, *c, *se, *R;
    float *Wty, *Wsc, *Wag, *Wcomb, *vbase, *vag, *vbe, *Xs, *hall, *out;
};

// ---- Fold small encoders into W_ih blocks (K=128 each) ----
// x layout for W_ih rows: [coord 0:128 | type 128:256 | node 256:384 | scene 384:512 | agent 512:640]
__global__ __launch_bounds__(512) void k_fold(Params p) {
    const int blk = blockIdx.x, c = threadIdx.x;
    __shared__ float lrow[NH];
    __shared__ float b1[NH], b2[NH], b3[NH], b4[NH];
    if (blk < 184) {
        const float* src; int ihoff, row; float* dst;
        if (blk < 8)       { row = blk;      src = p.W_nt  + row * NH; ihoff = 128; dst = p.Wty; }
        else if (blk < 40) { row = blk - 8;  src = p.W_sc  + row * NH; ihoff = 384; dst = p.Wsc; }
        else if (blk < 56) { row = blk - 40; src = p.W_ag  + row * NH; ihoff = 512; dst = p.Wag; }
        else               { row = blk - 56; src = p.W_e2n + row * NH; ihoff = 256; dst = p.Wcomb; }
        if (c < NH) lrow[c] = src[c];
        __syncthreads();
        float acc = 0.f;
        for (int k = 0; k < NH; ++k) acc += lrow[k] * p.W_ih[(ihoff + k) * 512 + c];
        dst[row * 512 + c] = acc;
    } else {
        if (c < NH) { b1[c] = p.b_nt[c]; b2[c] = p.b_sc[c]; b3[c] = p.b_ag[c]; b4[c] = p.b_e2n[c]; }
        __syncthreads();
        float vb = p.b_ih[c] + p.b_hh[c], va = 0.f, ve = 0.f;
        for (int k = 0; k < NH; ++k) {
            vb += b1[k] * p.W_ih[(128 + k) * 512 + c] + b2[k] * p.W_ih[(384 + k) * 512 + c];
            va += b3[k] * p.W_ih[(512 + k) * 512 + c];
            ve += b4[k] * p.W_ih[(256 + k) * 512 + c];
        }
        p.vbase[c] = vb; p.vag[c] = va; p.vbe[c] = ve;
    }
}

// ---- R0[b,i,:] = sum_j edge0[b,i,j,:] in closed form ----
__global__ void k_r0(Params p) {
    const int row = blockIdx.x, n = threadIdx.x;
    const int b = row / NA, i = row % NA;
    __shared__ float lf[NA][6];
    __shared__ float lt[NA][NTY];
    __shared__ float sumf[6], sumt[NTY];
    if (threadIdx.x < NA) {
        int j = threadIdx.x, rj = b * NA + j;
        for (int k = 0; k < 3; ++k) {
            lf[j][k]     = p.ntraj[(rj * NT + 0) * 3 + k];
            lf[j][3 + k] = p.traj [(rj * NT + 0) * 3 + k];
        }
        for (int k = 0; k < NTY; ++k) lt[j][k] = p.ty[rj * NTY + k];
    }
    __syncthreads();
    if (threadIdx.x < 6) {
        float s = 0.f; for (int j = 0; j < NA; ++j) s += lf[j][threadIdx.x];
        sumf[threadIdx.x] = s;
    } else if (threadIdx.x < 6 + NTY) {
        int k = threadIdx.x - 6; float s = 0.f;
        for (int j = 0; j < NA; ++j) s += lt[j][k];
        sumt[k] = s;
    }
    __syncthreads();
    float acc_i = p.b_ein[n] + p.b_ety[n];
    for (int k = 0; k < 6; ++k)   acc_i += lf[i][k] * p.W_ein[k * NH + n];
    for (int k = 0; k < NTY; ++k) acc_i += lt[i][k] * (p.W_ein[(12 + k) * NH + n] + p.W_ety[k * NH + n]);
    float acc_j = 0.f;
    for (int k = 0; k < 6; ++k)   acc_j += sumf[k] * p.W_ein[(6 + k) * NH + n];
    for (int k = 0; k < NTY; ++k) acc_j += sumt[k] * (p.W_ein[(20 + k) * NH + n] + p.W_ety[(NTY + k) * NH + n]);
    p.R[row * NH + n] = 64.f * acc_i + acc_j;
}

// ---- X_static[(g,t), 512] : all state-independent gate contributions ----
__global__ __launch_bounds__(512) void k_xstatic(Params p) {
    const int g = blockIdx.x, tid = threadIdx.x, b = g >> 6;
    __shared__ float coordL[NT][NH];
    __shared__ float sceneL[NT][NSC];
    __shared__ float agentL[NT][NAG];
    __shared__ float tyL[NTY];
    const float relv = p.rel[g];
    for (int idx = tid; idx < NT * NH; idx += 512) {
        int r = idx >> 7, k = idx & 127;
        float acc = p.b_in[k];
        const float* nt = p.ntraj + (g * NT + r) * 3;
        const float* tr = p.traj  + (g * NT + r) * 3;
        for (int j = 0; j < 3; ++j) acc += nt[j] * p.W_in[j * NH + k] + tr[j] * p.W_in[(3 + j) * NH + k];
        coordL[r][k] = fmaxf(acc, 0.f);
    }
    // FIX(round 2 bug): grid-stride loads — previous one-shot conditionals
    // needed tid up to 583 in a 512-thread block, leaving agentL rows 8-11
    // and all of tyL uninitialized (poison -> absmax ~1).
    for (int i = tid; i < NT * NSC; i += 512) { int r = i >> 5, k = i & 31; sceneL[r][k] = p.sd[(b * NT + r) * NSC + k]; }
    for (int i = tid; i < NT * NAG; i += 512) { int r = i >> 4, k = i & 15; agentL[r][k] = p.adata[(g * NT + r) * NAG + k] * relv; }
    if (tid < NTY) tyL[tid] = p.ty[g * NTY + tid];
    __syncthreads();
    const int c = tid;
    float base = p.vbase[c] + relv * p.vag[c];
    for (int i = 0; i < NTY; ++i) base += tyL[i] * p.Wty[i * 512 + c];
    float acc[NT];
#pragma unroll
    for (int r = 0; r < NT; ++r) acc[r] = base;
    for (int k = 0; k < NH; ++k) { float w = p.W_ih[k * 512 + c];
#pragma unroll
        for (int r = 0; r < NT; ++r) acc[r] += coordL[r][k] * w; }
    for (int k = 0; k < NSC; ++k) { float w = p.Wsc[k * 512 + c];
#pragma unroll
        for (int r = 0; r < NT; ++r) acc[r] += sceneL[r][k] * w; }
    for (int k = 0; k < NAG; ++k) { float w = p.Wag[k * 512 + c];
#pragma unroll
        for (int r = 0; r < NT; ++r) acc[r] += agentL[r][k] * w; }
#pragma unroll
    for (int r = 0; r < NT; ++r) p.Xs[((size_t)(g * NT + r)) * 512 + c] = acc[r];
}

// ---- One recurrence step: 2 rows/block, 256 blocks x 512 threads ----
__global__ __launch_bounds__(512) void k_step(Params p, int t) {
    const int tid = threadIdx.x;
    const int r0 = blockIdx.x * 2;
    const int b = r0 >> 6;
    const float* hcur = (t & 1) ? p.h1 : p.h0;
    float* hnxt = (t & 1) ? p.h0 : p.h1;

    __shared__ float lh[2][NH], lR[2][NH], lse[2][NH];
    __shared__ float psum[4][NH];
    __shared__ float hsumL[NH];
    __shared__ float lA[2][NH], lS[2][NH];
    __shared__ float lagg[2][NH];
    __shared__ float lg[2][512];
    __shared__ float tyL[2][NTY];

    // Stage 0: batch h-sum partials + own-row state loads.
    {
        const int n = tid & 127, q = tid >> 7;
        float s = 0.f;
        const float* hb = hcur + (b * NA + q * 16) * NH + n;
#pragma unroll
        for (int j = 0; j < 16; ++j) s += hb[j * NH];
        psum[q][n] = s;
    }
    for (int idx = tid; idx < 2 * NH; idx += 512) {
        int r = idx >> 7, k = idx & 127;
        lh[r][k]  = hcur[(r0 + r) * NH + k];
        lR[r][k]  = p.R [(r0 + r) * NH + k];
        lse[r][k] = p.se[(r0 + r) * NH + k];
    }
    if (tid < 16) { int r = tid >> 3, i = tid & 7; tyL[r][i] = p.ty[(r0 + r) * NTY + i]; }
    __syncthreads();
    if (tid < NH) hsumL[tid] = psum[0][tid] + psum[1][tid] + psum[2][tid] + psum[3][tid];
    __syncthreads();

    // Stage A: R_new (sg0) and se_new (sg1), 2 rows each.
    {
        const int n = tid & 127, sel = tid >> 7, r = sel & 1, sg = sel >> 1;
        if (sg == 0) {
            float a1 = 0.f, a2 = 0.f, a3 = 0.f;
            for (int k = 0; k < NH; ++k) {
                a1 += lh[r][k] * p.W_edge[k * NH + n];
                a2 += hsumL[k] * p.W_edge[(128 + k) * NH + n];
                a3 += lR[r][k] * p.W_edge[(256 + k) * NH + n];
            }
            lA[r][n] = 64.f * a1 + a2 + a3 + 64.f * p.b_edge[n];
        } else {
            float s = 0.f;
            for (int k = 0; k < NH; ++k)
                s += lh[r][k] * p.W_self[k * NH + n] + lse[r][k] * p.W_self[(128 + k) * NH + n];
            for (int i = 0; i < NTY; ++i) s += tyL[r][i] * p.W_self[(256 + i) * NH + n];
            lS[r][n] = s + p.b_self[n];
        }
    }
    __syncthreads();
    if (tid < 256) {
        int r = tid >> 7, n = tid & 127;
        float Rn = lA[r][n], Sn = lS[r][n];
        p.R [(r0 + r) * NH + n] = Rn;
        p.se[(r0 + r) * NH + n] = Sn;
        lagg[r][n] = Rn + Sn;
    }
    __syncthreads();

    // Stage C: gates = X_static + (t>0)(agg@Wcomb + vbe) + h@W_hh
    {
        const int c = tid;
        float a0 = p.Xs[((size_t)(r0 * NT) + t) * 512 + c];
        float a1 = p.Xs[((size_t)((r0 + 1) * NT) + t) * 512 + c];
        if (t > 0) {
            float vb = p.vbe[c]; a0 += vb; a1 += vb;
            for (int k = 0; k < NH; ++k) {
                float w = p.Wcomb[k * 512 + c];
                a0 += lagg[0][k] * w; a1 += lagg[1][k] * w;
            }
        }
        for (int k = 0; k < NH; ++k) {
            float w = p.W_hh[k * 512 + c];
            a0 += lh[0][k] * w; a1 += lh[1][k] * w;
        }
        lg[0][c] = a0; lg[1][c] = a1;
    }
    __syncthreads();

    // Stage D: LSTM elementwise; write c, h_next, h_all.
    if (tid < 256) {
        const int r = tid >> 7, n = tid & 127, g = r0 + r;
        float gi = lg[r][n], gf = lg[r][128 + n], gg = lg[r][256 + n], go = lg[r][384 + n];
        float si = 1.f / (1.f + expf(-gi));
        float sf = 1.f / (1.f + expf(-gf));
        float so = 1.f / (1.f + expf(-go));
        float cn = sf * p.c[g * NH + n] + si * tanhf(gg);
        float hn = so * tanhf(cn);
        p.c[g * NH + n] = cn;
        hnxt[g * NH + n] = hn;
        p.hall[((size_t)g * NT + t) * NH + n] = hn;
    }
}

// ---- Output projection over all (g,t): relu(h @ W_pred + b_pred) ----
__global__ void k_out(Params p) {
    const int row0 = blockIdx.x * 8, tid = threadIdx.x;
    __shared__ float lhL[8][NH];
    for (int idx = tid; idx < 8 * NH; idx += 256) {
        int r = idx >> 7, k = idx & 127;
        lhL[r][k] = p.hall[((size_t)(row0 + r)) * NH + k];
    }
    __syncthreads();
    const int n = tid & 127, half = tid >> 7, rb = half * 4;
    float a0 = p.b_pred[n], a1 = a0, a2 = a0, a3 = a0;
    for (int k = 0; k < NH; ++k) {
        float w = p.W_pred[k * NH + n];
        a0 += lhL[rb][k] * w; a1 += lhL[rb + 1][k] * w;
        a2 += lhL[rb + 2][k] * w; a3 += lhL[rb + 3][k] * w;
    }
    p.out[((size_t)(row0 + rb))     * NH + n] = fmaxf(a0, 0.f);
    p.out[((size_t)(row0 + rb + 1)) * NH + n] = fmaxf(a1, 0.f);
    p.out[((size_t)(row0 + rb + 2)) * NH + n] = fmaxf(a2, 0.f);
    p.out[((size_t)(row0 + rb + 3)) * NH + n] = fmaxf(a3, 0.f);
}

extern "C" void kernel_launch(void* const* d_in, const int* in_sizes, int n_in,
                              void* d_out, int out_size, void* d_ws, size_t ws_size,
                              hipStream_t stream) {
    const float* const* in = (const float* const*)d_in;
    Params p;
    p.traj = in[0]; p.ntraj = in[1]; p.ty = in[2]; p.sd = in[3]; p.adata = in[4]; p.rel = in[5];
    p.W_in = in[6]; p.b_in = in[7]; p.W_nt = in[8]; p.b_nt = in[9];
    p.W_ag = in[10]; p.b_ag = in[11]; p.W_sc = in[12]; p.b_sc = in[13];
    p.W_ein = in[14]; p.b_ein = in[15]; p.W_ety = in[16]; p.b_ety = in[17];
    p.W_edge = in[18]; p.b_edge = in[19]; p.W_self = in[20]; p.b_self = in[21];
    p.W_e2n = in[22]; p.b_e2n = in[23];
    p.W_ih = in[24]; p.W_hh = in[25]; p.b_ih = in[26]; p.b_hh = in[27];
    p.W_pred = in[28]; p.b_pred = in[29];

    float* ws = (float*)d_ws;
    const size_t S = (size_t)NB * NA * NH;   // 65536
    p.h0 = ws;                // zeroed
    p.h1 = ws + S;            // zeroed
    p.c  = ws + 2 * S;        // zeroed
    p.se = ws + 3 * S;        // zeroed
    p.R  = ws + 4 * S;        // written by k_r0
    float* w = ws + 5 * S;
    p.Wty   = w;              w += 8 * 512;
    p.Wsc   = w;              w += 32 * 512;
    p.Wag   = w;              w += 16 * 512;
    p.Wcomb = w;              w += 128 * 512;
    p.vbase = w;              w += 512;
    p.vag   = w;              w += 512;
    p.vbe   = w;              w += 512;
    p.Xs    = w;              w += (size_t)NB * NA * NT * 512;
    p.hall  = w;              w += (size_t)NB * NA * NT * NH;
    p.out = (float*)d_out;

    hipMemsetAsync(p.h0, 0, 4 * S * sizeof(float), stream);   // h0,h1,c,se contiguous
    k_fold<<<185, 512, 0, stream>>>(p);
    k_r0<<<NB * NA, 128, 0, stream>>>(p);
    k_xstatic<<<NB * NA, 512, 0, stream>>>(p);
    for (int t = 0; t < NT; ++t)
        k_step<<<NB * NA / 2, 512, 0, stream>>>(p, t);
    k_out<<<NB * NA * NT / 8, 256, 0, stream>>>(p);
}